// Round 8
// baseline (1198.820 us; speedup 1.0000x reference)
//
#include <hip/hip_runtime.h>

#define TPB 256
constexpr int HID = 16;
constexpr int NC  = 8;
constexpr int NPB = 512;      // nodes per bucket (2^9)
constexpr int LOG_NPB = 9;
constexpr int MAXBK = 1024;   // max buckets supported by scan/LDS tables
constexpr int P1B = 512;      // pass-1 blocks

// ---- fp32 atomic add via native global_atomic_add_f32 ----
__device__ __forceinline__ void atomAddF(float* p, float v) {
    unsafeAtomicAdd(p, v);
}

// Detect whether edge_index arrived as int64 (little-endian: odd 32-bit words
// are the high halves, all zero since 0 <= idx < 100000) or int32.
__global__ void detect64_kernel(const int* __restrict__ ei, int E, int* flag) {
    int l = threadIdx.x;
    int v = 0;
    if (l < 32 && 2 * l + 1 < 2 * E) v = ei[2 * l + 1];
    unsigned long long b = __ballot(v != 0);
    if (l == 0) *flag = (b == 0ULL) ? 1 : 0;
}

// Load edge endpoint: index = row*E + e (row 0 = src, row 1 = dst).
__device__ __forceinline__ int edge_at(const int* __restrict__ ei, int index, int is64) {
    return is64 ? ei[2 * index] : ei[index];
}

// ---------------- shared small kernels ----------------

__global__ void init_deg_kernel(float* deg, int N) {
    int i = blockIdx.x * TPB + threadIdx.x;
    if (i < N) deg[i] = 1.0f;
}

__global__ void init_cnt_kernel(int* cnt, int N) {
    int i = blockIdx.x * TPB + threadIdx.x;
    if (i < N) cnt[i] = 0;
}

__global__ void dis_kernel(float* deg, int N) {
    int i = blockIdx.x * TPB + threadIdx.x;
    if (i < N) deg[i] = rsqrtf(deg[i]);
}

// ---------------- GEMMs (r4-proven) ----------------

// h1 = x @ W1, one row per thread (unscaled — atomic fallback).
__global__ void gemm1_kernel(const float* __restrict__ x, const float* __restrict__ W,
                             float* __restrict__ h, int N, int K) {
    int row = blockIdx.x * TPB + threadIdx.x;
    if (row >= N) return;
    const float* xr = x + (size_t)row * K;
    float acc[HID];
#pragma unroll
    for (int j = 0; j < HID; ++j) acc[j] = 0.f;
    for (int k = 0; k < K; k += 4) {
        float4 xv = *reinterpret_cast<const float4*>(xr + k);
        const float* Wk = W + (size_t)k * HID;
#pragma unroll
        for (int kk = 0; kk < 4; ++kk) {
            float xs = (&xv.x)[kk];
#pragma unroll
            for (int j = 0; j < HID; ++j)
                acc[j] = fmaf(xs, Wk[kk * HID + j], acc[j]);
        }
    }
    float* hr = h + (size_t)row * HID;
#pragma unroll
    for (int j = 0; j < HID; j += 4)
        *reinterpret_cast<float4*>(hr + j) = make_float4(acc[j], acc[j+1], acc[j+2], acc[j+3]);
}

// h1s = dis[row] * (x @ W1)
__global__ void gemm1s_kernel(const float* __restrict__ x, const float* __restrict__ W,
                              const float* __restrict__ dis, float* __restrict__ h, int N, int K) {
    int row = blockIdx.x * TPB + threadIdx.x;
    if (row >= N) return;
    const float* xr = x + (size_t)row * K;
    float acc[HID];
#pragma unroll
    for (int j = 0; j < HID; ++j) acc[j] = 0.f;
    for (int k = 0; k < K; k += 4) {
        float4 xv = *reinterpret_cast<const float4*>(xr + k);
        const float* Wk = W + (size_t)k * HID;
#pragma unroll
        for (int kk = 0; kk < 4; ++kk) {
            float xs = (&xv.x)[kk];
#pragma unroll
            for (int j = 0; j < HID; ++j)
                acc[j] = fmaf(xs, Wk[kk * HID + j], acc[j]);
        }
    }
    float d = dis[row];
#pragma unroll
    for (int j = 0; j < HID; ++j) acc[j] *= d;
    float* hr = h + (size_t)row * HID;
#pragma unroll
    for (int j = 0; j < HID; j += 4)
        *reinterpret_cast<float4*>(hr + j) = make_float4(acc[j], acc[j+1], acc[j+2], acc[j+3]);
}

// h2 = relu(agg1) @ W2 (unscaled — atomic fallback).
__global__ void gemm2_kernel(const float* __restrict__ agg1, const float* __restrict__ W2,
                             float* __restrict__ h2, int N) {
    int i = blockIdx.x * TPB + threadIdx.x;
    if (i >= N) return;
    const float* a = agg1 + (size_t)i * HID;
    float hv[HID];
#pragma unroll
    for (int k = 0; k < HID; k += 4) {
        float4 v = *reinterpret_cast<const float4*>(a + k);
        hv[k]     = fmaxf(v.x, 0.f);
        hv[k + 1] = fmaxf(v.y, 0.f);
        hv[k + 2] = fmaxf(v.z, 0.f);
        hv[k + 3] = fmaxf(v.w, 0.f);
    }
    float acc[NC];
#pragma unroll
    for (int c = 0; c < NC; ++c) acc[c] = 0.f;
#pragma unroll
    for (int k = 0; k < HID; ++k)
#pragma unroll
        for (int c = 0; c < NC; ++c)
            acc[c] = fmaf(hv[k], W2[k * NC + c], acc[c]);
    float* o = h2 + (size_t)i * NC;
    *reinterpret_cast<float4*>(o)     = make_float4(acc[0], acc[1], acc[2], acc[3]);
    *reinterpret_cast<float4*>(o + 4) = make_float4(acc[4], acc[5], acc[6], acc[7]);
}

// h2s = dis[i] * (relu(agg1) @ W2)
__global__ void gemm2s_kernel(const float* __restrict__ agg1, const float* __restrict__ W2,
                              const float* __restrict__ dis, float* __restrict__ h2, int N) {
    int i = blockIdx.x * TPB + threadIdx.x;
    if (i >= N) return;
    const float* a = agg1 + (size_t)i * HID;
    float hv[HID];
#pragma unroll
    for (int k = 0; k < HID; k += 4) {
        float4 v = *reinterpret_cast<const float4*>(a + k);
        hv[k]     = fmaxf(v.x, 0.f);
        hv[k + 1] = fmaxf(v.y, 0.f);
        hv[k + 2] = fmaxf(v.z, 0.f);
        hv[k + 3] = fmaxf(v.w, 0.f);
    }
    float acc[NC];
#pragma unroll
    for (int c = 0; c < NC; ++c) acc[c] = 0.f;
#pragma unroll
    for (int k = 0; k < HID; ++k)
#pragma unroll
        for (int c = 0; c < NC; ++c)
            acc[c] = fmaf(hv[k], W2[k * NC + c], acc[c]);
    float d = dis[i];
#pragma unroll
    for (int c = 0; c < NC; ++c) acc[c] *= d;
    float* o = h2 + (size_t)i * NC;
    *reinterpret_cast<float4*>(o)     = make_float4(acc[0], acc[1], acc[2], acc[3]);
    *reinterpret_cast<float4*>(o + 4) = make_float4(acc[4], acc[5], acc[6], acc[7]);
}

// ---------------- partition path (primary): no-global-atomic counting sort ----------------
// part[] entry: .x = w_bits, .y = src | (dstlow << 17)   (src < 2^17, dstlow < 512)

__global__ void zero_tot_kernel(int* tot, int NBK) {
    int i = blockIdx.x * TPB + threadIdx.x;
    if (i < NBK) tot[i] = 0;
}

// pass-1 histogram: LDS bucket counts per block -> hist[b][k], atomicAdd totals.
__global__ void p1hist_kernel(const int* __restrict__ ei, int* __restrict__ hist,
                              int* __restrict__ tot, int E, int NBK,
                              const int* __restrict__ flag) {
    __shared__ int lh[MAXBK];
    int t = threadIdx.x;
    for (int i = t; i < NBK; i += TPB) lh[i] = 0;
    __syncthreads();
    int is64 = *flag;
    int CH = (E + gridDim.x - 1) / gridDim.x;
    int s = blockIdx.x * CH;
    int e2 = min(E, s + CH);
    for (int i = s + t; i < e2; i += TPB) {
        int dst = edge_at(ei, E + i, is64);
        atomicAdd(&lh[dst >> LOG_NPB], 1);
    }
    __syncthreads();
    for (int i = t; i < NBK; i += TPB) {
        int v = lh[i];
        hist[(size_t)blockIdx.x * NBK + i] = v;
        if (v) atomicAdd(&tot[i], v);
    }
}

// single-block exclusive scan of tot -> base, cursor (verified scanB structure)
__global__ void p1scan_kernel(const int* __restrict__ tot, int* __restrict__ base,
                              int* __restrict__ cursor, int NBK, int E) {
    __shared__ int s[1024];
    int t = threadIdx.x;
    int v = (t < NBK) ? tot[t] : 0;
    s[t] = v;
    __syncthreads();
    for (int o = 1; o < 1024; o <<= 1) {
        int u = (t >= o) ? s[t - o] : 0;
        __syncthreads();
        s[t] += u;
        __syncthreads();
    }
    if (t < NBK) { base[t] = s[t] - v; cursor[t] = s[t] - v; }
    if (t == 0) base[NBK] = E;
}

// pass-1 scatter: block claims per-bucket ranges (1 atomic per (block,bucket)),
// then writes packed entries into its contiguous runs. LDS atomics only per edge.
__global__ void p1scatter_kernel(const int* __restrict__ ei, const float* __restrict__ w,
                                 const int* __restrict__ hist, int* __restrict__ cursor,
                                 uint2* __restrict__ part, int E, int NBK,
                                 const int* __restrict__ flag) {
    __shared__ int startk[MAXBK];
    __shared__ int loc[MAXBK];
    int t = threadIdx.x;
    for (int i = t; i < NBK; i += TPB) {
        int hv = hist[(size_t)blockIdx.x * NBK + i];
        startk[i] = hv ? atomicAdd(&cursor[i], hv) : 0;
        loc[i] = 0;
    }
    __syncthreads();
    int is64 = *flag;
    int CH = (E + gridDim.x - 1) / gridDim.x;
    int s = blockIdx.x * CH;
    int e2 = min(E, s + CH);
    for (int i = s + t; i < e2; i += TPB) {
        int src = edge_at(ei, i, is64);
        int dst = edge_at(ei, E + i, is64);
        float wv = w[i];
        int k = dst >> LOG_NPB;
        int dl = dst & (NPB - 1);
        int pos = startk[k] + atomicAdd(&loc[k], 1);
        part[pos] = make_uint2(__float_as_uint(wv), (unsigned)src | ((unsigned)dl << 17));
    }
}

// per-bucket weighted degree -> dis, all in LDS.
__global__ void degB_kernel(const uint2* __restrict__ part, const int* __restrict__ base,
                            float* __restrict__ dis, int N) {
    __shared__ float dacc[NPB];
    int k = blockIdx.x, t = threadIdx.x;
    for (int r = t; r < NPB; r += TPB) dacc[r] = 1.0f;   // self-loop weight
    __syncthreads();
    int s = base[k], e2 = base[k + 1];
    for (int i = s + t; i < e2; i += TPB) {
        uint2 en = part[i];
        atomicAdd(&dacc[(en.y >> 17) & (NPB - 1)], __uint_as_float(en.x));
    }
    __syncthreads();
    for (int r = t; r < NPB; r += TPB) {
        int node = (k << LOG_NPB) + r;
        if (node < N) dis[node] = rsqrtf(dacc[r]);
    }
}

// per-bucket layer-1 aggregation in LDS (rows padded to 17 to spread banks).
// agg1[dst][j] = b1[j] + dd*(h1s[dst][j] + sum_e w_e * h1s[src][j])
__global__ void aggB1_kernel(const uint2* __restrict__ part, const int* __restrict__ base,
                             const float* __restrict__ h1s, const float* __restrict__ dis,
                             const float* __restrict__ b1, float* __restrict__ agg1, int N) {
    __shared__ float acc[NPB * 17];
    int k = blockIdx.x, t = threadIdx.x;
    for (int idx = t; idx < NPB * HID; idx += TPB) {
        int r = idx >> 4, j = idx & 15;
        int node = (k << LOG_NPB) + r;
        acc[r * 17 + j] = (node < N) ? h1s[(size_t)node * HID + j] : 0.f;
    }
    __syncthreads();
    int s = base[k], e2 = base[k + 1];
    int g = t >> 4, j = t & 15;          // 16 groups x 16 feature-lanes
    for (int i = s + g; i < e2; i += 16) {
        uint2 en = part[i];
        float wv = __uint_as_float(en.x);
        int src = en.y & 0x1FFFF;
        int dl = (en.y >> 17) & (NPB - 1);
        atomicAdd(&acc[dl * 17 + j], wv * h1s[(size_t)src * HID + j]);
    }
    __syncthreads();
    for (int idx = t; idx < NPB * HID; idx += TPB) {
        int r = idx >> 4, jj = idx & 15;
        int node = (k << LOG_NPB) + r;
        if (node < N)
            agg1[(size_t)node * HID + jj] = b1[jj] + dis[node] * acc[r * 17 + jj];
    }
}

// per-bucket layer-2 aggregation + fused log_softmax (rows padded to 9).
__global__ void aggB2_lsm_kernel(const uint2* __restrict__ part, const int* __restrict__ base,
                                 const float* __restrict__ h2s, const float* __restrict__ dis,
                                 const float* __restrict__ b2, float* __restrict__ out, int N) {
    __shared__ float acc[NPB * 9];
    int k = blockIdx.x, t = threadIdx.x;
    for (int idx = t; idx < NPB * NC; idx += TPB) {
        int r = idx >> 3, j = idx & 7;
        int node = (k << LOG_NPB) + r;
        acc[r * 9 + j] = (node < N) ? h2s[(size_t)node * NC + j] : 0.f;
    }
    __syncthreads();
    int s = base[k], e2 = base[k + 1];
    int g = t >> 3, j = t & 7;           // 32 groups x 8 class-lanes
    for (int i = s + g; i < e2; i += 32) {
        uint2 en = part[i];
        float wv = __uint_as_float(en.x);
        int src = en.y & 0x1FFFF;
        int dl = (en.y >> 17) & (NPB - 1);
        atomicAdd(&acc[dl * 9 + j], wv * h2s[(size_t)src * NC + j]);
    }
    __syncthreads();
    for (int r = t; r < NPB; r += TPB) {
        int node = (k << LOG_NPB) + r;
        if (node >= N) continue;
        float dd = dis[node];
        float v[NC];
#pragma unroll
        for (int c = 0; c < NC; ++c) v[c] = b2[c] + dd * acc[r * 9 + c];
        float m = v[0];
#pragma unroll
        for (int c = 1; c < NC; ++c) m = fmaxf(m, v[c]);
        float ssum = 0.f;
#pragma unroll
        for (int c = 0; c < NC; ++c) ssum += expf(v[c] - m);
        float lse = m + logf(ssum);
        float* o = out + (size_t)node * NC;
        *reinterpret_cast<float4*>(o)     = make_float4(v[0]-lse, v[1]-lse, v[2]-lse, v[3]-lse);
        *reinterpret_cast<float4*>(o + 4) = make_float4(v[4]-lse, v[5]-lse, v[6]-lse, v[7]-lse);
    }
}

// ---------------- padded-bucket path (r4-proven fallback) ----------------

__global__ void scatterP_kernel(const int* __restrict__ ei, const float* __restrict__ w,
                                int* __restrict__ cnt, uint2* __restrict__ edata,
                                int E, int C, const int* __restrict__ flag) {
    int e = blockIdx.x * TPB + threadIdx.x;
    if (e >= E) return;
    int is64 = *flag;
    int src = edge_at(ei, e, is64);
    int dst = edge_at(ei, E + e, is64);
    float wv = w[e];
    int pos = atomicAdd(&cnt[dst], 1);
    if (pos < C)
        edata[(size_t)dst * C + pos] = make_uint2((unsigned)src, __float_as_uint(wv));
}

__global__ void degP_kernel(const uint2* __restrict__ edata, const int* __restrict__ cnt,
                            float* __restrict__ dis, int N, int C) {
    int wid = (blockIdx.x * blockDim.x + threadIdx.x) >> 6;
    if (wid >= N) return;
    int lane = threadIdx.x & 63;
    int m = cnt[wid]; if (m > C) m = C;
    const uint2* seg = edata + (size_t)wid * C;
    float s = 0.f;
    for (int i = lane; i < m; i += 64) s += __uint_as_float(seg[i].y);
#pragma unroll
    for (int o = 1; o < 64; o <<= 1) s += __shfl_xor(s, o, 64);
    if (lane == 0) dis[wid] = rsqrtf(1.0f + s);
}

__global__ void agg1P_kernel(const uint2* __restrict__ edata, const int* __restrict__ cnt,
                             const float* __restrict__ h1s, const float* __restrict__ dis,
                             const float* __restrict__ b1, float* __restrict__ agg1,
                             int N, int C) {
    int wid = (blockIdx.x * blockDim.x + threadIdx.x) >> 6;
    if (wid >= N) return;
    int lane = threadIdx.x & 63;
    int m = cnt[wid]; if (m > C) m = C;
    const uint2* seg = edata + (size_t)wid * C;
    float acc[HID];
#pragma unroll
    for (int j = 0; j < HID; ++j) acc[j] = 0.f;
    for (int i = lane; i < m; i += 64) {
        uint2 u = seg[i];
        float wv = __uint_as_float(u.y);
        const float* hr = h1s + (size_t)u.x * HID;
        float4 a = *reinterpret_cast<const float4*>(hr);
        float4 b = *reinterpret_cast<const float4*>(hr + 4);
        float4 c = *reinterpret_cast<const float4*>(hr + 8);
        float4 d = *reinterpret_cast<const float4*>(hr + 12);
        acc[0]  = fmaf(wv, a.x, acc[0]);  acc[1]  = fmaf(wv, a.y, acc[1]);
        acc[2]  = fmaf(wv, a.z, acc[2]);  acc[3]  = fmaf(wv, a.w, acc[3]);
        acc[4]  = fmaf(wv, b.x, acc[4]);  acc[5]  = fmaf(wv, b.y, acc[5]);
        acc[6]  = fmaf(wv, b.z, acc[6]);  acc[7]  = fmaf(wv, b.w, acc[7]);
        acc[8]  = fmaf(wv, c.x, acc[8]);  acc[9]  = fmaf(wv, c.y, acc[9]);
        acc[10] = fmaf(wv, c.z, acc[10]); acc[11] = fmaf(wv, c.w, acc[11]);
        acc[12] = fmaf(wv, d.x, acc[12]); acc[13] = fmaf(wv, d.y, acc[13]);
        acc[14] = fmaf(wv, d.z, acc[14]); acc[15] = fmaf(wv, d.w, acc[15]);
    }
#pragma unroll
    for (int j = 0; j < HID; ++j) {
        acc[j] += __shfl_xor(acc[j], 16, 64);
        acc[j] += __shfl_xor(acc[j], 32, 64);
    }
#pragma unroll
    for (int t = 0; t < 8; ++t) {
        float lo = __shfl_xor(acc[t], 8, 64);
        float hi = __shfl_xor(acc[t + 8], 8, 64);
        acc[t] = (lane & 8) ? (acc[t + 8] + hi) : (acc[t] + lo);
    }
#pragma unroll
    for (int t = 0; t < 4; ++t) {
        float lo = __shfl_xor(acc[t], 4, 64);
        float hi = __shfl_xor(acc[t + 4], 4, 64);
        acc[t] = (lane & 4) ? (acc[t + 4] + hi) : (acc[t] + lo);
    }
#pragma unroll
    for (int t = 0; t < 2; ++t) {
        float lo = __shfl_xor(acc[t], 2, 64);
        float hi = __shfl_xor(acc[t + 2], 2, 64);
        acc[t] = (lane & 2) ? (acc[t + 2] + hi) : (acc[t] + lo);
    }
    {
        float lo = __shfl_xor(acc[0], 1, 64);
        float hi = __shfl_xor(acc[1], 1, 64);
        acc[0] = (lane & 1) ? (acc[1] + hi) : (acc[0] + lo);
    }
    if (lane < HID) {
        float dd = dis[wid];
        agg1[(size_t)wid * HID + lane] =
            b1[lane] + dd * (h1s[(size_t)wid * HID + lane] + acc[0]);
    }
}

__global__ void agg2P_lsm_kernel(const uint2* __restrict__ edata, const int* __restrict__ cnt,
                                 const float* __restrict__ h2s, const float* __restrict__ dis,
                                 const float* __restrict__ b2, float* __restrict__ out,
                                 int N, int C) {
    int wid = (blockIdx.x * blockDim.x + threadIdx.x) >> 6;
    if (wid >= N) return;
    int lane = threadIdx.x & 63;
    int m = cnt[wid]; if (m > C) m = C;
    const uint2* seg = edata + (size_t)wid * C;
    float acc[NC];
#pragma unroll
    for (int j = 0; j < NC; ++j) acc[j] = 0.f;
    for (int i = lane; i < m; i += 64) {
        uint2 u = seg[i];
        float wv = __uint_as_float(u.y);
        const float* hr = h2s + (size_t)u.x * NC;
        float4 a = *reinterpret_cast<const float4*>(hr);
        float4 b = *reinterpret_cast<const float4*>(hr + 4);
        acc[0] = fmaf(wv, a.x, acc[0]);  acc[1] = fmaf(wv, a.y, acc[1]);
        acc[2] = fmaf(wv, a.z, acc[2]);  acc[3] = fmaf(wv, a.w, acc[3]);
        acc[4] = fmaf(wv, b.x, acc[4]);  acc[5] = fmaf(wv, b.y, acc[5]);
        acc[6] = fmaf(wv, b.z, acc[6]);  acc[7] = fmaf(wv, b.w, acc[7]);
    }
#pragma unroll
    for (int j = 0; j < NC; ++j) {
        acc[j] += __shfl_xor(acc[j], 8, 64);
        acc[j] += __shfl_xor(acc[j], 16, 64);
        acc[j] += __shfl_xor(acc[j], 32, 64);
    }
#pragma unroll
    for (int t = 0; t < 4; ++t) {
        float lo = __shfl_xor(acc[t], 4, 64);
        float hi = __shfl_xor(acc[t + 4], 4, 64);
        acc[t] = (lane & 4) ? (acc[t + 4] + hi) : (acc[t] + lo);
    }
#pragma unroll
    for (int t = 0; t < 2; ++t) {
        float lo = __shfl_xor(acc[t], 2, 64);
        float hi = __shfl_xor(acc[t + 2], 2, 64);
        acc[t] = (lane & 2) ? (acc[t + 2] + hi) : (acc[t] + lo);
    }
    {
        float lo = __shfl_xor(acc[0], 1, 64);
        float hi = __shfl_xor(acc[1], 1, 64);
        acc[0] = (lane & 1) ? (acc[1] + hi) : (acc[0] + lo);
    }
    int c = lane & 7;
    float dd = dis[wid];
    float v = b2[c] + dd * (h2s[(size_t)wid * NC + c] + acc[0]);
    float mx = v;
    mx = fmaxf(mx, __shfl_xor(mx, 1, 64));
    mx = fmaxf(mx, __shfl_xor(mx, 2, 64));
    mx = fmaxf(mx, __shfl_xor(mx, 4, 64));
    float ex = expf(v - mx);
    float ssum = ex;
    ssum += __shfl_xor(ssum, 1, 64);
    ssum += __shfl_xor(ssum, 2, 64);
    ssum += __shfl_xor(ssum, 4, 64);
    float r = v - mx - logf(ssum);
    if (lane < NC) out[(size_t)wid * NC + lane] = r;
}

// ---------------- atomic path (last-resort fallback) ----------------

__global__ void deg_edge_kernel(const int* __restrict__ ei, const float* __restrict__ w,
                                float* deg, int E, const int* __restrict__ flag) {
    int e = blockIdx.x * TPB + threadIdx.x;
    if (e >= E) return;
    int is64 = *flag;
    int dst = edge_at(ei, E + e, is64);
    atomAddF(&deg[dst], w[e]);
}

__global__ void init_agg1_kernel(const float* __restrict__ h1, const float* __restrict__ dis,
                                 const float* __restrict__ b1, float* __restrict__ agg1, int N) {
    int t = blockIdx.x * TPB + threadIdx.x;
    if (t >= N * HID) return;
    int i = t >> 4, j = t & 15;
    float d = dis[i];
    agg1[t] = b1[j] + d * d * h1[t];
}

__global__ void edge1_kernel(const int* __restrict__ ei, const float* __restrict__ w,
                             const float* __restrict__ dis, const float* __restrict__ h1,
                             float* __restrict__ agg1, int E, const int* __restrict__ flag) {
    int t = blockIdx.x * TPB + threadIdx.x;
    if (t >= E * HID) return;
    int e = t >> 4, j = t & 15;
    int is64 = *flag;
    int src = edge_at(ei, e, is64);
    int dst = edge_at(ei, E + e, is64);
    float nrm = dis[src] * w[e] * dis[dst];
    atomAddF(&agg1[dst * HID + j], nrm * h1[src * HID + j]);
}

__global__ void init_out_kernel(const float* __restrict__ h2, const float* __restrict__ dis,
                                const float* __restrict__ b2, float* __restrict__ out, int N) {
    int t = blockIdx.x * TPB + threadIdx.x;
    if (t >= N * NC) return;
    int i = t >> 3, j = t & 7;
    float d = dis[i];
    out[t] = b2[j] + d * d * h2[t];
}

__global__ void edge2_kernel(const int* __restrict__ ei, const float* __restrict__ w,
                             const float* __restrict__ dis, const float* __restrict__ h2,
                             float* __restrict__ out, int E, const int* __restrict__ flag) {
    int t = blockIdx.x * TPB + threadIdx.x;
    if (t >= E * NC) return;
    int e = t >> 3, j = t & 7;
    int is64 = *flag;
    int src = edge_at(ei, e, is64);
    int dst = edge_at(ei, E + e, is64);
    float nrm = dis[src] * w[e] * dis[dst];
    atomAddF(&out[dst * NC + j], nrm * h2[src * NC + j]);
}

__global__ void lsm_kernel(float* __restrict__ out, int N) {
    int i = blockIdx.x * TPB + threadIdx.x;
    if (i >= N) return;
    float* r = out + (size_t)i * NC;
    float4 a = *reinterpret_cast<const float4*>(r);
    float4 b = *reinterpret_cast<const float4*>(r + 4);
    float v[NC] = {a.x, a.y, a.z, a.w, b.x, b.y, b.z, b.w};
    float m = v[0];
#pragma unroll
    for (int j = 1; j < NC; ++j) m = fmaxf(m, v[j]);
    float s = 0.f;
#pragma unroll
    for (int j = 0; j < NC; ++j) s += expf(v[j] - m);
    float lse = m + logf(s);
#pragma unroll
    for (int j = 0; j < NC; ++j) v[j] -= lse;
    *reinterpret_cast<float4*>(r)     = make_float4(v[0], v[1], v[2], v[3]);
    *reinterpret_cast<float4*>(r + 4) = make_float4(v[4], v[5], v[6], v[7]);
}

extern "C" void kernel_launch(void* const* d_in, const int* in_sizes, int n_in,
                              void* d_out, int out_size, void* d_ws, size_t ws_size,
                              hipStream_t stream) {
    const float* x  = (const float*)d_in[0];
    const int*   ei = (const int*)d_in[1];
    const float* w  = (const float*)d_in[2];
    const float* W1 = (const float*)d_in[3];
    const float* b1 = (const float*)d_in[4];
    const float* W2 = (const float*)d_in[5];
    const float* b2 = (const float*)d_in[6];
    float* out = (float*)d_out;

    int E = in_sizes[2];          // 3,200,000
    int N = out_size / NC;        // 100,000
    int K = in_sizes[0] / N;      // 512

    auto nb = [](long long n) { return (int)((n + TPB - 1) / TPB); };

    // ---- partition path: exact counting sort, no per-edge global atomics ----
    int NBK = (N + NPB - 1) >> LOG_NPB;
    size_t need_part = (size_t)4 * ((size_t)2 * E + (size_t)41 * N
                                    + (size_t)P1B * NBK + 3 * (size_t)NBK + 8);
    bool okpart = (N <= (1 << 17)) && (NBK <= MAXBK) && (ws_size >= need_part);

    if (okpart) {
        uint2* part  = (uint2*)d_ws;                       // E entries
        float* h1s   = (float*)(part + E);                 // 16N (dis-scaled)
        float* agg1  = h1s + (size_t)N * HID;              // 16N
        float* h2s   = agg1 + (size_t)N * HID;             // 8N (dis-scaled)
        float* dis   = h2s + (size_t)N * NC;               // N
        int*   hist  = (int*)(dis + N);                    // P1B*NBK
        int*   tot   = hist + (size_t)P1B * NBK;           // NBK
        int*   base  = tot + NBK;                          // NBK+1
        int*   cursor= base + NBK + 1;                     // NBK
        int*   flag  = cursor + NBK;                       // 1

        detect64_kernel<<<1, 64, 0, stream>>>(ei, E, flag);
        zero_tot_kernel<<<nb(NBK), TPB, 0, stream>>>(tot, NBK);
        p1hist_kernel<<<P1B, TPB, 0, stream>>>(ei, hist, tot, E, NBK, flag);
        p1scan_kernel<<<1, 1024, 0, stream>>>(tot, base, cursor, NBK, E);
        p1scatter_kernel<<<P1B, TPB, 0, stream>>>(ei, w, hist, cursor, part, E, NBK, flag);
        degB_kernel<<<NBK, TPB, 0, stream>>>(part, base, dis, N);
        gemm1s_kernel<<<nb(N), TPB, 0, stream>>>(x, W1, dis, h1s, N, K);
        aggB1_kernel<<<NBK, TPB, 0, stream>>>(part, base, h1s, dis, b1, agg1, N);
        gemm2s_kernel<<<nb(N), TPB, 0, stream>>>(agg1, W2, dis, h2s, N);
        aggB2_lsm_kernel<<<NBK, TPB, 0, stream>>>(part, base, h2s, dis, b2, out, N);
        return;
    }

    // ---- padded-bucket path (r4-proven fallback) ----
    int C = 0;
    {
        int cands[3] = {96, 88, 80};
        for (int ci = 0; ci < 3; ++ci) {
            size_t need = (size_t)4 * ((size_t)2 * N * cands[ci] + (size_t)42 * N + 1);
            if (ws_size >= need) { C = cands[ci]; break; }
        }
    }
    int waveblocks = (int)(((long long)N * 64 + TPB - 1) / TPB);

    if (C > 0) {
        uint2* edata = (uint2*)d_ws;
        float* h1s   = (float*)(edata + (size_t)N * C);
        float* agg1  = h1s + (size_t)N * HID;
        float* h2s   = agg1 + (size_t)N * HID;
        float* dis   = h2s + (size_t)N * NC;
        int*   cnt   = (int*)(dis + N);
        int*   flag  = cnt + N;

        detect64_kernel<<<1, 64, 0, stream>>>(ei, E, flag);
        init_cnt_kernel<<<nb(N), TPB, 0, stream>>>(cnt, N);
        scatterP_kernel<<<nb(E), TPB, 0, stream>>>(ei, w, cnt, edata, E, C, flag);
        degP_kernel<<<waveblocks, TPB, 0, stream>>>(edata, cnt, dis, N, C);
        gemm1s_kernel<<<nb(N), TPB, 0, stream>>>(x, W1, dis, h1s, N, K);
        agg1P_kernel<<<waveblocks, TPB, 0, stream>>>(edata, cnt, h1s, dis, b1, agg1, N, C);
        gemm2s_kernel<<<nb(N), TPB, 0, stream>>>(agg1, W2, dis, h2s, N);
        agg2P_lsm_kernel<<<waveblocks, TPB, 0, stream>>>(edata, cnt, h2s, dis, b2, out, N, C);
        return;
    }

    // ---- atomic path (last resort) ----
    {
        float* deg  = (float*)d_ws;
        float* h1   = deg + N;
        float* agg1 = h1 + (size_t)N * HID;
        float* h2   = agg1 + (size_t)N * HID;
        int*   flag = (int*)(h2 + (size_t)N * NC);

        detect64_kernel<<<1, 64, 0, stream>>>(ei, E, flag);
        init_deg_kernel<<<nb(N), TPB, 0, stream>>>(deg, N);
        deg_edge_kernel<<<nb(E), TPB, 0, stream>>>(ei, w, deg, E, flag);
        dis_kernel<<<nb(N), TPB, 0, stream>>>(deg, N);
        gemm1_kernel<<<nb(N), TPB, 0, stream>>>(x, W1, h1, N, K);
        init_agg1_kernel<<<nb((long long)N * HID), TPB, 0, stream>>>(h1, deg, b1, agg1, N);
        edge1_kernel<<<nb((long long)E * HID), TPB, 0, stream>>>(ei, w, deg, h1, agg1, E, flag);
        gemm2_kernel<<<nb(N), TPB, 0, stream>>>(agg1, W2, h2, N);
        init_out_kernel<<<nb((long long)N * NC), TPB, 0, stream>>>(h2, deg, b2, out, N);
        edge2_kernel<<<nb((long long)E * NC), TPB, 0, stream>>>(ei, w, deg, h2, out, E, flag);
        lsm_kernel<<<nb(N), TPB, 0, stream>>>(out, N);
    }
}

// Round 9
// 605.294 us; speedup vs baseline: 1.9806x; 1.9806x over previous
//
#include <hip/hip_runtime.h>

#define TPB 256
constexpr int HID = 16;
constexpr int NC  = 8;
constexpr int NPB = 512;      // nodes per bucket (2^9)
constexpr int LOG_NPB = 9;
constexpr int MAXBK = 1024;   // max buckets supported by scan/LDS tables
constexpr int P1B = 512;      // pass-1 blocks

// ---- fp32 atomic add via native global_atomic_add_f32 ----
__device__ __forceinline__ void atomAddF(float* p, float v) {
    unsafeAtomicAdd(p, v);
}

// Detect whether edge_index arrived as int64 (little-endian: odd 32-bit words
// are the high halves, all zero since 0 <= idx < 100000) or int32.
__global__ void detect64_kernel(const int* __restrict__ ei, int E, int* flag) {
    int l = threadIdx.x;
    int v = 0;
    if (l < 32 && 2 * l + 1 < 2 * E) v = ei[2 * l + 1];
    unsigned long long b = __ballot(v != 0);
    if (l == 0) *flag = (b == 0ULL) ? 1 : 0;
}

// Load edge endpoint: index = row*E + e (row 0 = src, row 1 = dst).
__device__ __forceinline__ int edge_at(const int* __restrict__ ei, int index, int is64) {
    return is64 ? ei[2 * index] : ei[index];
}

// ---------------- shared small kernels ----------------

__global__ void init_deg_kernel(float* deg, int N) {
    int i = blockIdx.x * TPB + threadIdx.x;
    if (i < N) deg[i] = 1.0f;
}

__global__ void init_cnt_kernel(int* cnt, int N) {
    int i = blockIdx.x * TPB + threadIdx.x;
    if (i < N) cnt[i] = 0;
}

__global__ void dis_kernel(float* deg, int N) {
    int i = blockIdx.x * TPB + threadIdx.x;
    if (i < N) deg[i] = rsqrtf(deg[i]);
}

// ---------------- GEMMs (r4-proven) ----------------

__global__ void gemm1_kernel(const float* __restrict__ x, const float* __restrict__ W,
                             float* __restrict__ h, int N, int K) {
    int row = blockIdx.x * TPB + threadIdx.x;
    if (row >= N) return;
    const float* xr = x + (size_t)row * K;
    float acc[HID];
#pragma unroll
    for (int j = 0; j < HID; ++j) acc[j] = 0.f;
    for (int k = 0; k < K; k += 4) {
        float4 xv = *reinterpret_cast<const float4*>(xr + k);
        const float* Wk = W + (size_t)k * HID;
#pragma unroll
        for (int kk = 0; kk < 4; ++kk) {
            float xs = (&xv.x)[kk];
#pragma unroll
            for (int j = 0; j < HID; ++j)
                acc[j] = fmaf(xs, Wk[kk * HID + j], acc[j]);
        }
    }
    float* hr = h + (size_t)row * HID;
#pragma unroll
    for (int j = 0; j < HID; j += 4)
        *reinterpret_cast<float4*>(hr + j) = make_float4(acc[j], acc[j+1], acc[j+2], acc[j+3]);
}

__global__ void gemm1s_kernel(const float* __restrict__ x, const float* __restrict__ W,
                              const float* __restrict__ dis, float* __restrict__ h, int N, int K) {
    int row = blockIdx.x * TPB + threadIdx.x;
    if (row >= N) return;
    const float* xr = x + (size_t)row * K;
    float acc[HID];
#pragma unroll
    for (int j = 0; j < HID; ++j) acc[j] = 0.f;
    for (int k = 0; k < K; k += 4) {
        float4 xv = *reinterpret_cast<const float4*>(xr + k);
        const float* Wk = W + (size_t)k * HID;
#pragma unroll
        for (int kk = 0; kk < 4; ++kk) {
            float xs = (&xv.x)[kk];
#pragma unroll
            for (int j = 0; j < HID; ++j)
                acc[j] = fmaf(xs, Wk[kk * HID + j], acc[j]);
        }
    }
    float d = dis[row];
#pragma unroll
    for (int j = 0; j < HID; ++j) acc[j] *= d;
    float* hr = h + (size_t)row * HID;
#pragma unroll
    for (int j = 0; j < HID; j += 4)
        *reinterpret_cast<float4*>(hr + j) = make_float4(acc[j], acc[j+1], acc[j+2], acc[j+3]);
}

__global__ void gemm2_kernel(const float* __restrict__ agg1, const float* __restrict__ W2,
                             float* __restrict__ h2, int N) {
    int i = blockIdx.x * TPB + threadIdx.x;
    if (i >= N) return;
    const float* a = agg1 + (size_t)i * HID;
    float hv[HID];
#pragma unroll
    for (int k = 0; k < HID; k += 4) {
        float4 v = *reinterpret_cast<const float4*>(a + k);
        hv[k]     = fmaxf(v.x, 0.f);
        hv[k + 1] = fmaxf(v.y, 0.f);
        hv[k + 2] = fmaxf(v.z, 0.f);
        hv[k + 3] = fmaxf(v.w, 0.f);
    }
    float acc[NC];
#pragma unroll
    for (int c = 0; c < NC; ++c) acc[c] = 0.f;
#pragma unroll
    for (int k = 0; k < HID; ++k)
#pragma unroll
        for (int c = 0; c < NC; ++c)
            acc[c] = fmaf(hv[k], W2[k * NC + c], acc[c]);
    float* o = h2 + (size_t)i * NC;
    *reinterpret_cast<float4*>(o)     = make_float4(acc[0], acc[1], acc[2], acc[3]);
    *reinterpret_cast<float4*>(o + 4) = make_float4(acc[4], acc[5], acc[6], acc[7]);
}

__global__ void gemm2s_kernel(const float* __restrict__ agg1, const float* __restrict__ W2,
                              const float* __restrict__ dis, float* __restrict__ h2, int N) {
    int i = blockIdx.x * TPB + threadIdx.x;
    if (i >= N) return;
    const float* a = agg1 + (size_t)i * HID;
    float hv[HID];
#pragma unroll
    for (int k = 0; k < HID; k += 4) {
        float4 v = *reinterpret_cast<const float4*>(a + k);
        hv[k]     = fmaxf(v.x, 0.f);
        hv[k + 1] = fmaxf(v.y, 0.f);
        hv[k + 2] = fmaxf(v.z, 0.f);
        hv[k + 3] = fmaxf(v.w, 0.f);
    }
    float acc[NC];
#pragma unroll
    for (int c = 0; c < NC; ++c) acc[c] = 0.f;
#pragma unroll
    for (int k = 0; k < HID; ++k)
#pragma unroll
        for (int c = 0; c < NC; ++c)
            acc[c] = fmaf(hv[k], W2[k * NC + c], acc[c]);
    float d = dis[i];
#pragma unroll
    for (int c = 0; c < NC; ++c) acc[c] *= d;
    float* o = h2 + (size_t)i * NC;
    *reinterpret_cast<float4*>(o)     = make_float4(acc[0], acc[1], acc[2], acc[3]);
    *reinterpret_cast<float4*>(o + 4) = make_float4(acc[4], acc[5], acc[6], acc[7]);
}

// ---------------- sorted-CSR path (primary) ----------------
// Stage A (measured-cheap, r8): bucket partition, no per-edge global atomics.
// part[] entry: .x = w_bits, .y = src | (dstlow << 17)
// Stage B (new): per-bucket node sort -> sorted[] (src, w_bits) + rowoff[N+1] CSR.
// Stage C: r4-verified wave-per-node consumption over CSR (25600-block grids).

__global__ void zero_tot_kernel(int* tot, int NBK) {
    int i = blockIdx.x * TPB + threadIdx.x;
    if (i < NBK) tot[i] = 0;
}

__global__ void p1hist_kernel(const int* __restrict__ ei, int* __restrict__ hist,
                              int* __restrict__ tot, int E, int NBK,
                              const int* __restrict__ flag) {
    __shared__ int lh[MAXBK];
    int t = threadIdx.x;
    for (int i = t; i < NBK; i += TPB) lh[i] = 0;
    __syncthreads();
    int is64 = *flag;
    int CH = (E + gridDim.x - 1) / gridDim.x;
    int s = blockIdx.x * CH;
    int e2 = min(E, s + CH);
    for (int i = s + t; i < e2; i += TPB) {
        int dst = edge_at(ei, E + i, is64);
        atomicAdd(&lh[dst >> LOG_NPB], 1);
    }
    __syncthreads();
    for (int i = t; i < NBK; i += TPB) {
        int v = lh[i];
        hist[(size_t)blockIdx.x * NBK + i] = v;
        if (v) atomicAdd(&tot[i], v);
    }
}

// single-block exclusive scan of tot -> base, cursor; also rowoff[N] = E.
__global__ void p1scan_kernel(const int* __restrict__ tot, int* __restrict__ base,
                              int* __restrict__ cursor, int NBK, int E,
                              int* __restrict__ rowoffN) {
    __shared__ int s[1024];
    int t = threadIdx.x;
    int v = (t < NBK) ? tot[t] : 0;
    s[t] = v;
    __syncthreads();
    for (int o = 1; o < 1024; o <<= 1) {
        int u = (t >= o) ? s[t - o] : 0;
        __syncthreads();
        s[t] += u;
        __syncthreads();
    }
    if (t < NBK) { base[t] = s[t] - v; cursor[t] = s[t] - v; }
    if (t == 0) { base[NBK] = E; *rowoffN = E; }
}

__global__ void p1scatter_kernel(const int* __restrict__ ei, const float* __restrict__ w,
                                 const int* __restrict__ hist, int* __restrict__ cursor,
                                 uint2* __restrict__ part, int E, int NBK,
                                 const int* __restrict__ flag) {
    __shared__ int startk[MAXBK];
    __shared__ int loc[MAXBK];
    int t = threadIdx.x;
    for (int i = t; i < NBK; i += TPB) {
        int hv = hist[(size_t)blockIdx.x * NBK + i];
        startk[i] = hv ? atomicAdd(&cursor[i], hv) : 0;
        loc[i] = 0;
    }
    __syncthreads();
    int is64 = *flag;
    int CH = (E + gridDim.x - 1) / gridDim.x;
    int s = blockIdx.x * CH;
    int e2 = min(E, s + CH);
    for (int i = s + t; i < e2; i += TPB) {
        int src = edge_at(ei, i, is64);
        int dst = edge_at(ei, E + i, is64);
        float wv = w[i];
        int k = dst >> LOG_NPB;
        int dl = dst & (NPB - 1);
        int pos = startk[k] + atomicAdd(&loc[k], 1);
        part[pos] = make_uint2(__float_as_uint(wv), (unsigned)src | ((unsigned)dl << 17));
    }
}

// Stage B: per-bucket node sort. One 512-thread block per bucket.
// cnt/scan over NPB=512 with 512 threads = the verified scanB pattern.
__global__ void bsort_kernel(const uint2* __restrict__ part, const int* __restrict__ base,
                             uint2* __restrict__ sorted, int* __restrict__ rowoff, int N) {
    __shared__ int cnt[NPB];
    __shared__ int s[NPB];
    __shared__ int cur[NPB];
    int k = blockIdx.x, t = threadIdx.x;   // blockDim.x == NPB == 512
    cnt[t] = 0;
    __syncthreads();
    int s0 = base[k], e0 = base[k + 1];
    for (int i = s0 + t; i < e0; i += NPB)
        atomicAdd(&cnt[(part[i].y >> 17) & (NPB - 1)], 1);
    __syncthreads();
    int v = cnt[t];
    s[t] = v;
    __syncthreads();
    for (int o = 1; o < NPB; o <<= 1) {
        int u = (t >= o) ? s[t - o] : 0;
        __syncthreads();
        s[t] += u;
        __syncthreads();
    }
    int ex = s[t] - v;                     // exclusive prefix within bucket
    cur[t] = ex;
    int node = (k << LOG_NPB) + t;
    if (node < N) rowoff[node] = s0 + ex;
    __syncthreads();
    for (int i = s0 + t; i < e0; i += NPB) {
        uint2 en = part[i];
        int dl = (en.y >> 17) & (NPB - 1);
        int pos = s0 + atomicAdd(&cur[dl], 1);
        sorted[pos] = make_uint2(en.y & 0x1FFFF, en.x);   // (src, w_bits)
    }
}

// Stage C: wave-per-node over CSR — r4-verified bodies, rowoff indexing.

__global__ void degC_kernel(const uint2* __restrict__ sorted, const int* __restrict__ rowoff,
                            float* __restrict__ dis, int N) {
    int wid = (blockIdx.x * blockDim.x + threadIdx.x) >> 6;
    if (wid >= N) return;
    int lane = threadIdx.x & 63;
    int s = rowoff[wid];
    int m = rowoff[wid + 1] - s;
    const uint2* seg = sorted + s;
    float sum = 0.f;
    for (int i = lane; i < m; i += 64) sum += __uint_as_float(seg[i].y);
#pragma unroll
    for (int o = 1; o < 64; o <<= 1) sum += __shfl_xor(sum, o, 64);
    if (lane == 0) dis[wid] = rsqrtf(1.0f + sum);
}

__global__ void agg1C_kernel(const uint2* __restrict__ sorted, const int* __restrict__ rowoff,
                             const float* __restrict__ h1s, const float* __restrict__ dis,
                             const float* __restrict__ b1, float* __restrict__ agg1, int N) {
    int wid = (blockIdx.x * blockDim.x + threadIdx.x) >> 6;
    if (wid >= N) return;
    int lane = threadIdx.x & 63;
    int s = rowoff[wid];
    int m = rowoff[wid + 1] - s;
    const uint2* seg = sorted + s;
    float acc[HID];
#pragma unroll
    for (int j = 0; j < HID; ++j) acc[j] = 0.f;
    for (int i = lane; i < m; i += 64) {
        uint2 u = seg[i];
        float wv = __uint_as_float(u.y);
        const float* hr = h1s + (size_t)u.x * HID;
        float4 a = *reinterpret_cast<const float4*>(hr);
        float4 b = *reinterpret_cast<const float4*>(hr + 4);
        float4 c = *reinterpret_cast<const float4*>(hr + 8);
        float4 d = *reinterpret_cast<const float4*>(hr + 12);
        acc[0]  = fmaf(wv, a.x, acc[0]);  acc[1]  = fmaf(wv, a.y, acc[1]);
        acc[2]  = fmaf(wv, a.z, acc[2]);  acc[3]  = fmaf(wv, a.w, acc[3]);
        acc[4]  = fmaf(wv, b.x, acc[4]);  acc[5]  = fmaf(wv, b.y, acc[5]);
        acc[6]  = fmaf(wv, b.z, acc[6]);  acc[7]  = fmaf(wv, b.w, acc[7]);
        acc[8]  = fmaf(wv, c.x, acc[8]);  acc[9]  = fmaf(wv, c.y, acc[9]);
        acc[10] = fmaf(wv, c.z, acc[10]); acc[11] = fmaf(wv, c.w, acc[11]);
        acc[12] = fmaf(wv, d.x, acc[12]); acc[13] = fmaf(wv, d.y, acc[13]);
        acc[14] = fmaf(wv, d.z, acc[14]); acc[15] = fmaf(wv, d.w, acc[15]);
    }
#pragma unroll
    for (int j = 0; j < HID; ++j) {
        acc[j] += __shfl_xor(acc[j], 16, 64);
        acc[j] += __shfl_xor(acc[j], 32, 64);
    }
#pragma unroll
    for (int t = 0; t < 8; ++t) {
        float lo = __shfl_xor(acc[t], 8, 64);
        float hi = __shfl_xor(acc[t + 8], 8, 64);
        acc[t] = (lane & 8) ? (acc[t + 8] + hi) : (acc[t] + lo);
    }
#pragma unroll
    for (int t = 0; t < 4; ++t) {
        float lo = __shfl_xor(acc[t], 4, 64);
        float hi = __shfl_xor(acc[t + 4], 4, 64);
        acc[t] = (lane & 4) ? (acc[t + 4] + hi) : (acc[t] + lo);
    }
#pragma unroll
    for (int t = 0; t < 2; ++t) {
        float lo = __shfl_xor(acc[t], 2, 64);
        float hi = __shfl_xor(acc[t + 2], 2, 64);
        acc[t] = (lane & 2) ? (acc[t + 2] + hi) : (acc[t] + lo);
    }
    {
        float lo = __shfl_xor(acc[0], 1, 64);
        float hi = __shfl_xor(acc[1], 1, 64);
        acc[0] = (lane & 1) ? (acc[1] + hi) : (acc[0] + lo);
    }
    if (lane < HID) {
        float dd = dis[wid];
        agg1[(size_t)wid * HID + lane] =
            b1[lane] + dd * (h1s[(size_t)wid * HID + lane] + acc[0]);
    }
}

__global__ void agg2C_lsm_kernel(const uint2* __restrict__ sorted, const int* __restrict__ rowoff,
                                 const float* __restrict__ h2s, const float* __restrict__ dis,
                                 const float* __restrict__ b2, float* __restrict__ out, int N) {
    int wid = (blockIdx.x * blockDim.x + threadIdx.x) >> 6;
    if (wid >= N) return;
    int lane = threadIdx.x & 63;
    int s = rowoff[wid];
    int m = rowoff[wid + 1] - s;
    const uint2* seg = sorted + s;
    float acc[NC];
#pragma unroll
    for (int j = 0; j < NC; ++j) acc[j] = 0.f;
    for (int i = lane; i < m; i += 64) {
        uint2 u = seg[i];
        float wv = __uint_as_float(u.y);
        const float* hr = h2s + (size_t)u.x * NC;
        float4 a = *reinterpret_cast<const float4*>(hr);
        float4 b = *reinterpret_cast<const float4*>(hr + 4);
        acc[0] = fmaf(wv, a.x, acc[0]);  acc[1] = fmaf(wv, a.y, acc[1]);
        acc[2] = fmaf(wv, a.z, acc[2]);  acc[3] = fmaf(wv, a.w, acc[3]);
        acc[4] = fmaf(wv, b.x, acc[4]);  acc[5] = fmaf(wv, b.y, acc[5]);
        acc[6] = fmaf(wv, b.z, acc[6]);  acc[7] = fmaf(wv, b.w, acc[7]);
    }
#pragma unroll
    for (int j = 0; j < NC; ++j) {
        acc[j] += __shfl_xor(acc[j], 8, 64);
        acc[j] += __shfl_xor(acc[j], 16, 64);
        acc[j] += __shfl_xor(acc[j], 32, 64);
    }
#pragma unroll
    for (int t = 0; t < 4; ++t) {
        float lo = __shfl_xor(acc[t], 4, 64);
        float hi = __shfl_xor(acc[t + 4], 4, 64);
        acc[t] = (lane & 4) ? (acc[t + 4] + hi) : (acc[t] + lo);
    }
#pragma unroll
    for (int t = 0; t < 2; ++t) {
        float lo = __shfl_xor(acc[t], 2, 64);
        float hi = __shfl_xor(acc[t + 2], 2, 64);
        acc[t] = (lane & 2) ? (acc[t + 2] + hi) : (acc[t] + lo);
    }
    {
        float lo = __shfl_xor(acc[0], 1, 64);
        float hi = __shfl_xor(acc[1], 1, 64);
        acc[0] = (lane & 1) ? (acc[1] + hi) : (acc[0] + lo);
    }
    int c = lane & 7;
    float dd = dis[wid];
    float v = b2[c] + dd * (h2s[(size_t)wid * NC + c] + acc[0]);
    float mx = v;
    mx = fmaxf(mx, __shfl_xor(mx, 1, 64));
    mx = fmaxf(mx, __shfl_xor(mx, 2, 64));
    mx = fmaxf(mx, __shfl_xor(mx, 4, 64));
    float ex = expf(v - mx);
    float ssum = ex;
    ssum += __shfl_xor(ssum, 1, 64);
    ssum += __shfl_xor(ssum, 2, 64);
    ssum += __shfl_xor(ssum, 4, 64);
    float r = v - mx - logf(ssum);
    if (lane < NC) out[(size_t)wid * NC + lane] = r;
}

// ---------------- padded-bucket path (r4-proven fallback) ----------------

__global__ void scatterP_kernel(const int* __restrict__ ei, const float* __restrict__ w,
                                int* __restrict__ cnt, uint2* __restrict__ edata,
                                int E, int C, const int* __restrict__ flag) {
    int e = blockIdx.x * TPB + threadIdx.x;
    if (e >= E) return;
    int is64 = *flag;
    int src = edge_at(ei, e, is64);
    int dst = edge_at(ei, E + e, is64);
    float wv = w[e];
    int pos = atomicAdd(&cnt[dst], 1);
    if (pos < C)
        edata[(size_t)dst * C + pos] = make_uint2((unsigned)src, __float_as_uint(wv));
}

__global__ void degP_kernel(const uint2* __restrict__ edata, const int* __restrict__ cnt,
                            float* __restrict__ dis, int N, int C) {
    int wid = (blockIdx.x * blockDim.x + threadIdx.x) >> 6;
    if (wid >= N) return;
    int lane = threadIdx.x & 63;
    int m = cnt[wid]; if (m > C) m = C;
    const uint2* seg = edata + (size_t)wid * C;
    float s = 0.f;
    for (int i = lane; i < m; i += 64) s += __uint_as_float(seg[i].y);
#pragma unroll
    for (int o = 1; o < 64; o <<= 1) s += __shfl_xor(s, o, 64);
    if (lane == 0) dis[wid] = rsqrtf(1.0f + s);
}

__global__ void agg1P_kernel(const uint2* __restrict__ edata, const int* __restrict__ cnt,
                             const float* __restrict__ h1s, const float* __restrict__ dis,
                             const float* __restrict__ b1, float* __restrict__ agg1,
                             int N, int C) {
    int wid = (blockIdx.x * blockDim.x + threadIdx.x) >> 6;
    if (wid >= N) return;
    int lane = threadIdx.x & 63;
    int m = cnt[wid]; if (m > C) m = C;
    const uint2* seg = edata + (size_t)wid * C;
    float acc[HID];
#pragma unroll
    for (int j = 0; j < HID; ++j) acc[j] = 0.f;
    for (int i = lane; i < m; i += 64) {
        uint2 u = seg[i];
        float wv = __uint_as_float(u.y);
        const float* hr = h1s + (size_t)u.x * HID;
        float4 a = *reinterpret_cast<const float4*>(hr);
        float4 b = *reinterpret_cast<const float4*>(hr + 4);
        float4 c = *reinterpret_cast<const float4*>(hr + 8);
        float4 d = *reinterpret_cast<const float4*>(hr + 12);
        acc[0]  = fmaf(wv, a.x, acc[0]);  acc[1]  = fmaf(wv, a.y, acc[1]);
        acc[2]  = fmaf(wv, a.z, acc[2]);  acc[3]  = fmaf(wv, a.w, acc[3]);
        acc[4]  = fmaf(wv, b.x, acc[4]);  acc[5]  = fmaf(wv, b.y, acc[5]);
        acc[6]  = fmaf(wv, b.z, acc[6]);  acc[7]  = fmaf(wv, b.w, acc[7]);
        acc[8]  = fmaf(wv, c.x, acc[8]);  acc[9]  = fmaf(wv, c.y, acc[9]);
        acc[10] = fmaf(wv, c.z, acc[10]); acc[11] = fmaf(wv, c.w, acc[11]);
        acc[12] = fmaf(wv, d.x, acc[12]); acc[13] = fmaf(wv, d.y, acc[13]);
        acc[14] = fmaf(wv, d.z, acc[14]); acc[15] = fmaf(wv, d.w, acc[15]);
    }
#pragma unroll
    for (int j = 0; j < HID; ++j) {
        acc[j] += __shfl_xor(acc[j], 16, 64);
        acc[j] += __shfl_xor(acc[j], 32, 64);
    }
#pragma unroll
    for (int t = 0; t < 8; ++t) {
        float lo = __shfl_xor(acc[t], 8, 64);
        float hi = __shfl_xor(acc[t + 8], 8, 64);
        acc[t] = (lane & 8) ? (acc[t + 8] + hi) : (acc[t] + lo);
    }
#pragma unroll
    for (int t = 0; t < 4; ++t) {
        float lo = __shfl_xor(acc[t], 4, 64);
        float hi = __shfl_xor(acc[t + 4], 4, 64);
        acc[t] = (lane & 4) ? (acc[t + 4] + hi) : (acc[t] + lo);
    }
#pragma unroll
    for (int t = 0; t < 2; ++t) {
        float lo = __shfl_xor(acc[t], 2, 64);
        float hi = __shfl_xor(acc[t + 2], 2, 64);
        acc[t] = (lane & 2) ? (acc[t + 2] + hi) : (acc[t] + lo);
    }
    {
        float lo = __shfl_xor(acc[0], 1, 64);
        float hi = __shfl_xor(acc[1], 1, 64);
        acc[0] = (lane & 1) ? (acc[1] + hi) : (acc[0] + lo);
    }
    if (lane < HID) {
        float dd = dis[wid];
        agg1[(size_t)wid * HID + lane] =
            b1[lane] + dd * (h1s[(size_t)wid * HID + lane] + acc[0]);
    }
}

__global__ void agg2P_lsm_kernel(const uint2* __restrict__ edata, const int* __restrict__ cnt,
                                 const float* __restrict__ h2s, const float* __restrict__ dis,
                                 const float* __restrict__ b2, float* __restrict__ out,
                                 int N, int C) {
    int wid = (blockIdx.x * blockDim.x + threadIdx.x) >> 6;
    if (wid >= N) return;
    int lane = threadIdx.x & 63;
    int m = cnt[wid]; if (m > C) m = C;
    const uint2* seg = edata + (size_t)wid * C;
    float acc[NC];
#pragma unroll
    for (int j = 0; j < NC; ++j) acc[j] = 0.f;
    for (int i = lane; i < m; i += 64) {
        uint2 u = seg[i];
        float wv = __uint_as_float(u.y);
        const float* hr = h2s + (size_t)u.x * NC;
        float4 a = *reinterpret_cast<const float4*>(hr);
        float4 b = *reinterpret_cast<const float4*>(hr + 4);
        acc[0] = fmaf(wv, a.x, acc[0]);  acc[1] = fmaf(wv, a.y, acc[1]);
        acc[2] = fmaf(wv, a.z, acc[2]);  acc[3] = fmaf(wv, a.w, acc[3]);
        acc[4] = fmaf(wv, b.x, acc[4]);  acc[5] = fmaf(wv, b.y, acc[5]);
        acc[6] = fmaf(wv, b.z, acc[6]);  acc[7] = fmaf(wv, b.w, acc[7]);
    }
#pragma unroll
    for (int j = 0; j < NC; ++j) {
        acc[j] += __shfl_xor(acc[j], 8, 64);
        acc[j] += __shfl_xor(acc[j], 16, 64);
        acc[j] += __shfl_xor(acc[j], 32, 64);
    }
#pragma unroll
    for (int t = 0; t < 4; ++t) {
        float lo = __shfl_xor(acc[t], 4, 64);
        float hi = __shfl_xor(acc[t + 4], 4, 64);
        acc[t] = (lane & 4) ? (acc[t + 4] + hi) : (acc[t] + lo);
    }
#pragma unroll
    for (int t = 0; t < 2; ++t) {
        float lo = __shfl_xor(acc[t], 2, 64);
        float hi = __shfl_xor(acc[t + 2], 2, 64);
        acc[t] = (lane & 2) ? (acc[t + 2] + hi) : (acc[t] + lo);
    }
    {
        float lo = __shfl_xor(acc[0], 1, 64);
        float hi = __shfl_xor(acc[1], 1, 64);
        acc[0] = (lane & 1) ? (acc[1] + hi) : (acc[0] + lo);
    }
    int c = lane & 7;
    float dd = dis[wid];
    float v = b2[c] + dd * (h2s[(size_t)wid * NC + c] + acc[0]);
    float mx = v;
    mx = fmaxf(mx, __shfl_xor(mx, 1, 64));
    mx = fmaxf(mx, __shfl_xor(mx, 2, 64));
    mx = fmaxf(mx, __shfl_xor(mx, 4, 64));
    float ex = expf(v - mx);
    float ssum = ex;
    ssum += __shfl_xor(ssum, 1, 64);
    ssum += __shfl_xor(ssum, 2, 64);
    ssum += __shfl_xor(ssum, 4, 64);
    float r = v - mx - logf(ssum);
    if (lane < NC) out[(size_t)wid * NC + lane] = r;
}

// ---------------- atomic path (last-resort fallback) ----------------

__global__ void deg_edge_kernel(const int* __restrict__ ei, const float* __restrict__ w,
                                float* deg, int E, const int* __restrict__ flag) {
    int e = blockIdx.x * TPB + threadIdx.x;
    if (e >= E) return;
    int is64 = *flag;
    int dst = edge_at(ei, E + e, is64);
    atomAddF(&deg[dst], w[e]);
}

__global__ void init_agg1_kernel(const float* __restrict__ h1, const float* __restrict__ dis,
                                 const float* __restrict__ b1, float* __restrict__ agg1, int N) {
    int t = blockIdx.x * TPB + threadIdx.x;
    if (t >= N * HID) return;
    int i = t >> 4, j = t & 15;
    float d = dis[i];
    agg1[t] = b1[j] + d * d * h1[t];
}

__global__ void edge1_kernel(const int* __restrict__ ei, const float* __restrict__ w,
                             const float* __restrict__ dis, const float* __restrict__ h1,
                             float* __restrict__ agg1, int E, const int* __restrict__ flag) {
    int t = blockIdx.x * TPB + threadIdx.x;
    if (t >= E * HID) return;
    int e = t >> 4, j = t & 15;
    int is64 = *flag;
    int src = edge_at(ei, e, is64);
    int dst = edge_at(ei, E + e, is64);
    float nrm = dis[src] * w[e] * dis[dst];
    atomAddF(&agg1[dst * HID + j], nrm * h1[src * HID + j]);
}

__global__ void init_out_kernel(const float* __restrict__ h2, const float* __restrict__ dis,
                                const float* __restrict__ b2, float* __restrict__ out, int N) {
    int t = blockIdx.x * TPB + threadIdx.x;
    if (t >= N * NC) return;
    int i = t >> 3, j = t & 7;
    float d = dis[i];
    out[t] = b2[j] + d * d * h2[t];
}

__global__ void edge2_kernel(const int* __restrict__ ei, const float* __restrict__ w,
                             const float* __restrict__ dis, const float* __restrict__ h2,
                             float* __restrict__ out, int E, const int* __restrict__ flag) {
    int t = blockIdx.x * TPB + threadIdx.x;
    if (t >= E * NC) return;
    int e = t >> 3, j = t & 7;
    int is64 = *flag;
    int src = edge_at(ei, e, is64);
    int dst = edge_at(ei, E + e, is64);
    float nrm = dis[src] * w[e] * dis[dst];
    atomAddF(&out[dst * NC + j], nrm * h2[src * NC + j]);
}

__global__ void lsm_kernel(float* __restrict__ out, int N) {
    int i = blockIdx.x * TPB + threadIdx.x;
    if (i >= N) return;
    float* r = out + (size_t)i * NC;
    float4 a = *reinterpret_cast<const float4*>(r);
    float4 b = *reinterpret_cast<const float4*>(r + 4);
    float v[NC] = {a.x, a.y, a.z, a.w, b.x, b.y, b.z, b.w};
    float m = v[0];
#pragma unroll
    for (int j = 1; j < NC; ++j) m = fmaxf(m, v[j]);
    float s = 0.f;
#pragma unroll
    for (int j = 0; j < NC; ++j) s += expf(v[j] - m);
    float lse = m + logf(s);
#pragma unroll
    for (int j = 0; j < NC; ++j) v[j] -= lse;
    *reinterpret_cast<float4*>(r)     = make_float4(v[0], v[1], v[2], v[3]);
    *reinterpret_cast<float4*>(r + 4) = make_float4(v[4], v[5], v[6], v[7]);
}

extern "C" void kernel_launch(void* const* d_in, const int* in_sizes, int n_in,
                              void* d_out, int out_size, void* d_ws, size_t ws_size,
                              hipStream_t stream) {
    const float* x  = (const float*)d_in[0];
    const int*   ei = (const int*)d_in[1];
    const float* w  = (const float*)d_in[2];
    const float* W1 = (const float*)d_in[3];
    const float* b1 = (const float*)d_in[4];
    const float* W2 = (const float*)d_in[5];
    const float* b2 = (const float*)d_in[6];
    float* out = (float*)d_out;

    int E = in_sizes[2];          // 3,200,000
    int N = out_size / NC;        // 100,000
    int K = in_sizes[0] / N;      // 512

    auto nb = [](long long n) { return (int)((n + TPB - 1) / TPB); };
    int waveblocks = (int)(((long long)N * 64 + TPB - 1) / TPB);

    // ---- sorted-CSR path: counting-sort to per-node CSR, no per-edge global atomics ----
    int NBK = (N + NPB - 1) >> LOG_NPB;
    // words: part 2E + sorted 2E + h1s 16N + agg1 16N + h2s 8N + dis N + rowoff (N+1)
    //        + hist P1B*NBK + tot NBK + base NBK+1 + cursor NBK + flag 1
    size_t need_sort = (size_t)4 * ((size_t)4 * E + (size_t)42 * N
                                    + (size_t)P1B * NBK + 3 * (size_t)NBK + 8);
    bool oksort = (N <= (1 << 17)) && (NBK <= MAXBK) && (ws_size >= need_sort);

    if (oksort) {
        uint2* part   = (uint2*)d_ws;                      // E entries
        uint2* sorted = part + E;                          // E entries
        float* h1s    = (float*)(sorted + E);              // 16N (dis-scaled)
        float* agg1   = h1s + (size_t)N * HID;             // 16N
        float* h2s    = agg1 + (size_t)N * HID;            // 8N (dis-scaled)
        float* dis    = h2s + (size_t)N * NC;              // N
        int*   rowoff = (int*)(dis + N);                   // N+1
        int*   hist   = rowoff + N + 1;                    // P1B*NBK
        int*   tot    = hist + (size_t)P1B * NBK;          // NBK
        int*   base   = tot + NBK;                         // NBK+1
        int*   cursor = base + NBK + 1;                    // NBK
        int*   flag   = cursor + NBK;                      // 1

        detect64_kernel<<<1, 64, 0, stream>>>(ei, E, flag);
        zero_tot_kernel<<<nb(NBK), TPB, 0, stream>>>(tot, NBK);
        p1hist_kernel<<<P1B, TPB, 0, stream>>>(ei, hist, tot, E, NBK, flag);
        p1scan_kernel<<<1, 1024, 0, stream>>>(tot, base, cursor, NBK, E, rowoff + N);
        p1scatter_kernel<<<P1B, TPB, 0, stream>>>(ei, w, hist, cursor, part, E, NBK, flag);
        bsort_kernel<<<NBK, NPB, 0, stream>>>(part, base, sorted, rowoff, N);
        degC_kernel<<<waveblocks, TPB, 0, stream>>>(sorted, rowoff, dis, N);
        gemm1s_kernel<<<nb(N), TPB, 0, stream>>>(x, W1, dis, h1s, N, K);
        agg1C_kernel<<<waveblocks, TPB, 0, stream>>>(sorted, rowoff, h1s, dis, b1, agg1, N);
        gemm2s_kernel<<<nb(N), TPB, 0, stream>>>(agg1, W2, dis, h2s, N);
        agg2C_lsm_kernel<<<waveblocks, TPB, 0, stream>>>(sorted, rowoff, h2s, dis, b2, out, N);
        return;
    }

    // ---- padded-bucket path (r4-proven fallback) ----
    int C = 0;
    {
        int cands[3] = {96, 88, 80};
        for (int ci = 0; ci < 3; ++ci) {
            size_t need = (size_t)4 * ((size_t)2 * N * cands[ci] + (size_t)42 * N + 1);
            if (ws_size >= need) { C = cands[ci]; break; }
        }
    }

    if (C > 0) {
        uint2* edata = (uint2*)d_ws;
        float* h1s   = (float*)(edata + (size_t)N * C);
        float* agg1  = h1s + (size_t)N * HID;
        float* h2s   = agg1 + (size_t)N * HID;
        float* dis   = h2s + (size_t)N * NC;
        int*   cnt   = (int*)(dis + N);
        int*   flag  = cnt + N;

        detect64_kernel<<<1, 64, 0, stream>>>(ei, E, flag);
        init_cnt_kernel<<<nb(N), TPB, 0, stream>>>(cnt, N);
        scatterP_kernel<<<nb(E), TPB, 0, stream>>>(ei, w, cnt, edata, E, C, flag);
        degP_kernel<<<waveblocks, TPB, 0, stream>>>(edata, cnt, dis, N, C);
        gemm1s_kernel<<<nb(N), TPB, 0, stream>>>(x, W1, dis, h1s, N, K);
        agg1P_kernel<<<waveblocks, TPB, 0, stream>>>(edata, cnt, h1s, dis, b1, agg1, N, C);
        gemm2s_kernel<<<nb(N), TPB, 0, stream>>>(agg1, W2, dis, h2s, N);
        agg2P_lsm_kernel<<<waveblocks, TPB, 0, stream>>>(edata, cnt, h2s, dis, b2, out, N, C);
        return;
    }

    // ---- atomic path (last resort) ----
    {
        float* deg  = (float*)d_ws;
        float* h1   = deg + N;
        float* agg1 = h1 + (size_t)N * HID;
        float* h2   = agg1 + (size_t)N * HID;
        int*   flag = (int*)(h2 + (size_t)N * NC);

        detect64_kernel<<<1, 64, 0, stream>>>(ei, E, flag);
        init_deg_kernel<<<nb(N), TPB, 0, stream>>>(deg, N);
        deg_edge_kernel<<<nb(E), TPB, 0, stream>>>(ei, w, deg, E, flag);
        dis_kernel<<<nb(N), TPB, 0, stream>>>(deg, N);
        gemm1_kernel<<<nb(N), TPB, 0, stream>>>(x, W1, h1, N, K);
        init_agg1_kernel<<<nb((long long)N * HID), TPB, 0, stream>>>(h1, deg, b1, agg1, N);
        edge1_kernel<<<nb((long long)E * HID), TPB, 0, stream>>>(ei, w, deg, h1, agg1, E, flag);
        gemm2_kernel<<<nb(N), TPB, 0, stream>>>(agg1, W2, h2, N);
        init_out_kernel<<<nb((long long)N * NC), TPB, 0, stream>>>(h2, deg, b2, out, N);
        edge2_kernel<<<nb((long long)E * NC), TPB, 0, stream>>>(ei, w, deg, h2, out, E, flag);
        lsm_kernel<<<nb(N), TPB, 0, stream>>>(out, N);
    }
}